// Round 8
// baseline (622.120 us; speedup 1.0000x reference)
//
#include <hip/hip_runtime.h>
#include <hip/hip_bf16.h>

// SeqExperts: 64 experts, 128 tokens each, d_model=1024, d_hidden=4096.
// out[e*128+m] = relu(x_e @ W1[e]^T) @ W2[e]^T
// R3 (540): counted-vmcnt double-buffer, XCD swizzle, BK=32, 128x128 tile.
// R4 (794 FAIL): no-LDS direct-fragment. R5 (707 FAIL): broken staging coalescing.
// R6 (521, best): BK=64 + chunk-XOR swizzle + pack2 + nontemporal W + x->bf16 prepass.
// R7 (529): depth-3 pipeline -> flat; depth and strip-size exonerated.
// R8: OCCUPANCY test. Tile 128x64, BK=32 -> 24 KB LDS + ~120 VGPR ->
//     __launch_bounds__(256,4) -> 4 blocks/CU (16 waves/CU, 2x TLP).
//     Same proven 2-phase skeleton and swizzle as R7.

typedef __attribute__((ext_vector_type(8))) short bf16x8;   // 8 bf16 (4 VGPRs)
typedef __attribute__((ext_vector_type(4))) float f32x4;
typedef __attribute__((ext_vector_type(4))) unsigned int u32x4;

#define N_EXPERTS 64
#define DM 1024
#define DH 4096
#define TOKS 128

__device__ __forceinline__ unsigned f2u(float f) {
    union { float f; unsigned u; } v; v.f = f; return v.u;
}
// round-half-up fp32->bf16 (0.5 ulp; no NaN/inf in data)
__device__ __forceinline__ unsigned short f2bf(float f) {
    return (unsigned short)((f2u(f) + 0x8000u) >> 16);
}
// pack two fp32 -> 2xbf16 in one u32
__device__ __forceinline__ unsigned pack2(float lo, float hi) {
    return ((f2u(lo) + 0x8000u) >> 16) | ((f2u(hi) + 0x8000u) & 0xFFFF0000u);
}

// elementwise fp32 -> bf16 (8 elems/thread)
__global__ __launch_bounds__(256)
void cvt_bf16(const float* __restrict__ in, unsigned* __restrict__ outp, int n8) {
    int i = blockIdx.x * blockDim.x + threadIdx.x;
    if (i >= n8) return;
    const f32x4* p = (const f32x4*)in + (size_t)i * 2;
    f32x4 a = p[0], b = p[1];
    u32x4 o = { pack2(a[0], a[1]), pack2(a[2], a[3]),
                pack2(b[0], b[1]), pack2(b[2], b[3]) };
    *((u32x4*)outp + i) = o;
}

// C[128 x N] = A[128 x K] * B[N x K]^T for expert e; output tile 128 x 64.
// A: bf16 row-major lda=K. B: fp32 weights [N][K]. C: bf16+relu or fp32.
// LDS: sA[2][128][32], sB[2][64][32] bf16; 16B chunks swizzled c^((row>>1)&3).
template<int N, int K, bool RELU_OUT_BF16>
__global__ __launch_bounds__(256, 4)
void moe_gemm(const unsigned short* __restrict__ Ab, const float* __restrict__ Bp,
              void* __restrict__ Cp, int nwg_per_xcd)
{
    constexpr int BK = 32;
    constexpr int NT = K / BK;        // 32 (pass1) / 128 (pass2); even
    constexpr int NTILES = N / 64;    // 64 (pass1) / 16 (pass2)

    __shared__ unsigned short sA[2][128][BK];  // 8 KiB per buf
    __shared__ unsigned short sB[2][64][BK];   // 4 KiB per buf

    const int tid = threadIdx.x;
    const int bid = (blockIdx.x & 7) * nwg_per_xcd + (blockIdx.x >> 3);
    const int e   = bid / NTILES;
    const int nt  = bid % NTILES;

    const int lane = tid & 63;
    const int w    = tid >> 6;       // wave 0..3
    const int wr   = w >> 1;         // row half (0..1): rows wr*64..+63
    const int wc   = w & 1;          // col half (0..1): cols wc*32..+31
    const int lrow = lane & 15;
    const int kq   = lane >> 4;      // 0..3

    // ---- A staging (R7-verified): arow = tid>>2 (0..63; rows arow, arow+64), ac = tid&3.
    const int arow = tid >> 2;
    const int ac   = tid & 3;
    const int aswz = (arow >> 1) & 3;    // +64 preserves &3

    const unsigned short* aBase = Ab + (size_t)(e * TOKS + arow) * K + ac * 8;

    // ---- B staging: brow = tid>>2 (0..63), bc = tid&3; each thread loads 8 fp32
    //      (32 B contiguous) -> one full 16B bf16 chunk -> one ds_write_b128.
    const int brow = tid >> 2;
    const int bc   = tid & 3;
    const int bswz = (brow >> 1) & 3;
    const float* bBase = Bp + ((size_t)e * N + (size_t)nt * 64 + brow) * K + bc * 8;

    // ---- fragment-read chunk offset (R7-verified); all frag rows share (lrow>>1)&3.
    const int offk = (kq ^ ((lrow >> 1) & 3)) * 8;

    f32x4 acc[4][2];
    #pragma unroll
    for (int i = 0; i < 4; ++i)
        #pragma unroll
        for (int n = 0; n < 2; ++n)
            #pragma unroll
            for (int q = 0; q < 4; ++q) acc[i][n][q] = 0.f;

    struct SetA { u32x4 a[2]; };   // rows arow, arow+64
    struct SetB { f32x4 b[2]; };   // 8 fp32, row brow
    SetA sa0, sa1;
    SetB sb0, sb1;

    auto LOAD = [&](int t, SetA& A, SetB& B) {
        #pragma unroll
        for (int j = 0; j < 2; ++j)
            A.a[j] = *(const u32x4*)(aBase + (size_t)j * 64 * K + t * BK);
        const f32x4* p = (const f32x4*)(bBase + t * BK);
        B.b[0] = __builtin_nontemporal_load(p);
        B.b[1] = __builtin_nontemporal_load(p + 1);
    };

    auto WRITE = [&](int buf, SetA& A, SetB& B) {
        const int c8 = (ac ^ aswz) * 8;
        #pragma unroll
        for (int j = 0; j < 2; ++j)
            *(u32x4*)&sA[buf][arow + j * 64][c8] = A.a[j];
        u32x4 u = { pack2(B.b[0][0], B.b[0][1]), pack2(B.b[0][2], B.b[0][3]),
                    pack2(B.b[1][0], B.b[1][1]), pack2(B.b[1][2], B.b[1][3]) };
        *(u32x4*)&sB[buf][brow][(bc ^ bswz) * 8] = u;
    };

    auto COMPUTE = [&](int buf) {
        bf16x8 af[4], bfr[2];
        #pragma unroll
        for (int i = 0; i < 4; ++i)
            af[i] = *(const bf16x8*)&sA[buf][wr * 64 + i * 16 + lrow][offk];
        #pragma unroll
        for (int n = 0; n < 2; ++n)
            bfr[n] = *(const bf16x8*)&sB[buf][wc * 32 + n * 16 + lrow][offk];
        #pragma unroll
        for (int i = 0; i < 4; ++i)
            #pragma unroll
            for (int n = 0; n < 2; ++n)
                acc[i][n] = __builtin_amdgcn_mfma_f32_16x16x32_bf16(af[i], bfr[n], acc[i][n], 0, 0, 0);
    };

    // Prologue: 2 tiles in flight.
    LOAD(0, sa0, sb0);
    LOAD(1, sa1, sb1);
    WRITE(0, sa0, sb0);                    // counted vmcnt: waits only set 0
    asm volatile("s_waitcnt lgkmcnt(0)" ::: "memory");
    __builtin_amdgcn_s_barrier();

    for (int t = 0; t < NT; t += 2) {
        if (t + 2 < NT) LOAD(t + 2, sa0, sb0);
        COMPUTE(0);
        if (t + 1 < NT) WRITE(1, sa1, sb1);   // newer loads stay in flight
        asm volatile("s_waitcnt lgkmcnt(0)" ::: "memory");
        __builtin_amdgcn_s_barrier();

        if (t + 3 < NT) LOAD(t + 3, sa1, sb1);
        COMPUTE(1);
        if (t + 2 < NT) WRITE(0, sa0, sb0);
        asm volatile("s_waitcnt lgkmcnt(0)" ::: "memory");
        __builtin_amdgcn_s_barrier();
    }

    // Epilogue. C/D layout (m89-verified): col = lane&15, row = (lane>>4)*4 + reg
    const size_t crow0 = (size_t)e * TOKS;
    if constexpr (RELU_OUT_BF16) {
        unsigned short* C = (unsigned short*)Cp;
        #pragma unroll
        for (int i = 0; i < 4; ++i)
            #pragma unroll
            for (int n = 0; n < 2; ++n)
                #pragma unroll
                for (int q = 0; q < 4; ++q) {
                    const int row = wr * 64 + i * 16 + kq * 4 + q;
                    const int col = nt * 64 + wc * 32 + n * 16 + lrow;
                    C[(crow0 + row) * N + col] = f2bf(fmaxf(acc[i][n][q], 0.f));
                }
    } else {
        float* C = (float*)Cp;
        #pragma unroll
        for (int i = 0; i < 4; ++i)
            #pragma unroll
            for (int n = 0; n < 2; ++n)
                #pragma unroll
                for (int q = 0; q < 4; ++q) {
                    const int row = wr * 64 + i * 16 + kq * 4 + q;
                    const int col = nt * 64 + wc * 32 + n * 16 + lrow;
                    C[(crow0 + row) * N + col] = acc[i][n][q];
                }
    }
}

extern "C" void kernel_launch(void* const* d_in, const int* in_sizes, int n_in,
                              void* d_out, int out_size, void* d_ws, size_t ws_size,
                              hipStream_t stream) {
    const float* inputs = (const float*)d_in[0];   // [8192, 1024] fp32
    const float* w1     = (const float*)d_in[1];   // [64, 4096, 1024] fp32
    const float* w2     = (const float*)d_in[2];   // [64, 1024, 4096] fp32
    // d_in[3] = splits (always 128) -- unused

    unsigned short* h  = (unsigned short*)d_ws;                                     // 64 MiB
    unsigned short* xb = (unsigned short*)((char*)d_ws + (size_t)64 * 1024 * 1024); // 16 MiB
    float* out = (float*)d_out;

    // Pre-pass: x fp32 -> bf16
    const int n8 = (TOKS * N_EXPERTS) * DM / 8;    // 1,048,576
    cvt_bf16<<<dim3(n8 / 256), dim3(256), 0, stream>>>(inputs, (unsigned*)xb, n8);

    // Pass 1: h = relu(x @ w1^T), bf16. grid = 64*64 = 4096
    moe_gemm<DH, DM, true><<<dim3(N_EXPERTS * (DH / 64)), dim3(256), 0, stream>>>(
        xb, w1, h, N_EXPERTS * (DH / 64) / 8);
    // Pass 2: out = h @ w2^T, fp32. grid = 64*16 = 1024
    moe_gemm<DM, DH, false><<<dim3(N_EXPERTS * (DM / 64)), dim3(256), 0, stream>>>(
        h, w2, out, N_EXPERTS * (DM / 64) / 8);
}